// Round 4
// baseline (158.128 us; speedup 1.0000x reference)
//
#include <hip/hip_runtime.h>

// Triaffine span[b,x,y,z] = sum_{i,o,j} start[b,x,i] W[i,o,j] end[b,y,j] cls[b,z,o]
// B=8, L=256, Z=16, H=256. Contraction order o -> i -> j (12.9 GF), bf16 MFMA.
//   K1: Wc[bz,i,j]  = sum_o cls[bz,o] * W[i,o,j]      batch=i  (B=W TRANS-staged)
//   K2: T [bz,x,j]  = sum_i start[b,x,i] * Wc[bz,i,j] batch=bz (B=Wc TRANS-staged)
//   K3: tmp[bz,x,y] = sum_j T[bz,x,j] * end[b,y,j]    batch=bz (A@B^T, both natural)
//   K4: out[b,x,y,z] = tmp[(b,z),x,y]
// Round-4 changes (vs r3 which passed at 157us, GEMMs ~40us each):
//  * raw s_barrier + explicit lgkmcnt(0) only -- no vmcnt(0) drain at barriers,
//    so next-step global loads stay in flight across the barrier (T4/T14).
//  * double-buffered LDS, ONE barrier per K-step (other-buffer write is safe:
//    all waves passed this step's barrier => finished last step's reads).
//  * 512 threads / 8 waves (wave tile 32x64) -> 16 waves/CU latency hiding.
//  * ztranspose reads float4.

typedef __attribute__((ext_vector_type(8))) short          bf16x8;
typedef __attribute__((ext_vector_type(8))) unsigned short u16x8;
typedef __attribute__((ext_vector_type(4))) unsigned short u16x4;
typedef __attribute__((ext_vector_type(4))) float          f32x4;

#define LDST 40   // LDS row stride in shorts (80B rows: 16B-aligned, ~2-way banks)

__device__ __forceinline__ unsigned short f2bf(float f) {
    unsigned u = __builtin_bit_cast(unsigned, f);
    u += 0x7fff + ((u >> 16) & 1);            // RNE
    return (unsigned short)(u >> 16);
}

// 128x128 tile, K=256 (8 steps of BK=32), 512 threads = 8 waves (4m x 2n),
// wave tile 32x64 -> 2x4 fragments of 16x16x32.
// A global: [m][k] row-major. B global: BTRANS ? [k][n] : [n][k].
template<bool AB16, bool BB16, bool BTRANS, bool CB16>
__global__ __launch_bounds__(512, 4)
void gemm_mfma(const void* __restrict__ Abv, const void* __restrict__ Bbv,
               void* __restrict__ Cbv,
               int lda, int ldb, int ldc,
               long aBS, int aSh, long bBS, int bSh, long cBS)
{
    __shared__ unsigned short As[2][128 * LDST];
    __shared__ unsigned short Bs[2][128 * LDST];

    const int tid  = threadIdx.x;
    const int bz   = blockIdx.z;
    const int row0 = blockIdx.y * 128;
    const int col0 = blockIdx.x * 128;

    const float*          Af = (const float*)Abv          + (long)(bz >> aSh) * aBS;
    const unsigned short* Ah = (const unsigned short*)Abv + (long)(bz >> aSh) * aBS;
    const float*          Bf = (const float*)Bbv          + (long)(bz >> bSh) * bBS;
    const unsigned short* Bh = (const unsigned short*)Bbv + (long)(bz >> bSh) * bBS;
    float*          Cf = (float*)Cbv          + (long)bz * cBS;
    unsigned short* Ch = (unsigned short*)Cbv + (long)bz * cBS;

    // staging indices (512 threads)
    const int ar  = tid >> 2;         // 0..127 row (A / natural-B)
    const int akc = tid & 3;          // k-chunk of 8
    const int kp  = (tid >> 5) * 2;   // TRANS: k-row pair 0..30
    const int ng  = (tid & 31) * 4;   // TRANS: 4 n's, 0..124

    // compute indices
    const int wid = tid >> 6, lane = tid & 63;
    const int wm = wid >> 1, wn = wid & 1;        // 4 m-waves x 2 n-waves
    const int lr = lane & 15, lg = lane >> 4;

    f32x4 acc[2][4] = {};

    // prefetch registers (live across COMPUTE)
    float4 aPf[2]; u16x8 aPh;
    float4 bNf[2]; u16x8 bNh;
    float4 bTf[2]; u16x4 bTh[2];

    auto LOAD = [&](int k0) {
        if constexpr (!AB16) {
            const float* p = Af + (long)(row0 + ar) * lda + k0 + akc * 8;
            aPf[0] = *(const float4*)p;
            aPf[1] = *(const float4*)(p + 4);
        } else {
            aPh = *(const u16x8*)(Ah + (long)(row0 + ar) * lda + k0 + akc * 8);
        }
        if constexpr (!BTRANS) {
            if constexpr (!BB16) {
                const float* p = Bf + (long)(col0 + ar) * ldb + k0 + akc * 8;
                bNf[0] = *(const float4*)p;
                bNf[1] = *(const float4*)(p + 4);
            } else {
                bNh = *(const u16x8*)(Bh + (long)(col0 + ar) * ldb + k0 + akc * 8);
            }
        } else {
            if constexpr (!BB16) {
                const float* p = Bf + (long)(k0 + kp) * ldb + col0 + ng;
                bTf[0] = *(const float4*)p;
                bTf[1] = *(const float4*)(p + ldb);
            } else {
                const unsigned short* p = Bh + (long)(k0 + kp) * ldb + col0 + ng;
                bTh[0] = *(const u16x4*)p;
                bTh[1] = *(const u16x4*)(p + ldb);
            }
        }
    };

    auto WRITE = [&](int buf) {
        // A tile -> As[row][k]
        u16x8 w;
        if constexpr (!AB16) {
            const float* v = (const float*)&aPf[0];
#pragma unroll
            for (int e = 0; e < 8; ++e) w[e] = f2bf(v[e]);
        } else {
            w = aPh;
        }
        *(u16x8*)(As[buf] + ar * LDST + akc * 8) = w;

        if constexpr (!BTRANS) {
            u16x8 wb;
            if constexpr (!BB16) {
                const float* v = (const float*)&bNf[0];
#pragma unroll
                for (int e = 0; e < 8; ++e) wb[e] = f2bf(v[e]);
            } else {
                wb = bNh;
            }
            *(u16x8*)(Bs[buf] + ar * LDST + akc * 8) = wb;
        } else {
            // pack k-pair into b32, scatter over 4 n-rows
#pragma unroll
            for (int e = 0; e < 4; ++e) {
                unsigned lo, hi;
                if constexpr (!BB16) {
                    const float* v0 = (const float*)&bTf[0];
                    const float* v1 = (const float*)&bTf[1];
                    lo = f2bf(v0[e]); hi = f2bf(v1[e]);
                } else {
                    lo = bTh[0][e]; hi = bTh[1][e];
                }
                *(unsigned*)(Bs[buf] + (ng + e) * LDST + kp) = lo | (hi << 16);
            }
        }
    };

    auto COMPUTE = [&](int buf) {
        bf16x8 aF[2], bF[4];
#pragma unroll
        for (int fm = 0; fm < 2; ++fm)
            aF[fm] = *(const bf16x8*)&As[buf][(wm * 32 + fm * 16 + lr) * LDST + lg * 8];
#pragma unroll
        for (int fn = 0; fn < 4; ++fn)
            bF[fn] = *(const bf16x8*)&Bs[buf][(wn * 64 + fn * 16 + lr) * LDST + lg * 8];
        __builtin_amdgcn_s_setprio(1);
#pragma unroll
        for (int fm = 0; fm < 2; ++fm)
#pragma unroll
            for (int fn = 0; fn < 4; ++fn)
                acc[fm][fn] = __builtin_amdgcn_mfma_f32_16x16x32_bf16(
                    aF[fm], bF[fn], acc[fm][fn], 0, 0, 0);
        __builtin_amdgcn_s_setprio(0);
    };

    LOAD(0);
    WRITE(0);                          // compiler waits vmcnt before ds_writes
#pragma unroll
    for (int s = 0; s < 8; ++s) {
        if (s < 7) LOAD((s + 1) * 32);                 // issue early, no drain
        asm volatile("s_waitcnt lgkmcnt(0)" ::: "memory");  // own ds_writes visible
        __builtin_amdgcn_s_barrier();                  // raw barrier: vmcnt stays up
        COMPUTE(s & 1);
        if (s < 7) WRITE((s + 1) & 1);                 // other buffer: no barrier needed
    }

    // epilogue: C/D mapping col=lane&15, row=(lane>>4)*4+q  [m89-verified]
#pragma unroll
    for (int fm = 0; fm < 2; ++fm)
#pragma unroll
        for (int q = 0; q < 4; ++q) {
            const long row = row0 + wm * 32 + fm * 16 + lg * 4 + q;
#pragma unroll
            for (int fn = 0; fn < 4; ++fn) {
                const int col = col0 + wn * 64 + fn * 16 + lr;
                if constexpr (CB16) Ch[row * ldc + col] = f2bf(acc[fm][fn][q]);
                else                Cf[row * ldc + col] = acc[fm][fn][q];
            }
        }
}

// tmp[(b*16+z), x, y] fp32 -> out[((b*256+x)*256+y)*16+z]
__global__ __launch_bounds__(256)
void ztranspose(const float* __restrict__ tmp, float* __restrict__ out)
{
    __shared__ float lds[256][17];
    const int tid = threadIdx.x;
    const int b = blockIdx.x >> 8;
    const int x = blockIdx.x & 255;
    const int w = tid >> 6, l = tid & 63;

#pragma unroll
    for (int rep = 0; rep < 4; ++rep) {
        const int z = rep * 4 + w;
        float4 v = *(const float4*)(tmp + ((long)(b * 16 + z) * 256 + x) * 256 + l * 4);
        lds[l * 4 + 0][z] = v.x;
        lds[l * 4 + 1][z] = v.y;
        lds[l * 4 + 2][z] = v.z;
        lds[l * 4 + 3][z] = v.w;
    }
    __syncthreads();

    float* op = out + (long)(b * 256 + x) * 4096;
#pragma unroll
    for (int q = 0; q < 4; ++q) {
        const int y  = q * 64 + (tid >> 2);
        const int z0 = (tid & 3) * 4;
        float4 v = { lds[y][z0], lds[y][z0 + 1], lds[y][z0 + 2], lds[y][z0 + 3] };
        *(float4*)(op + (q * 256 + tid) * 4) = v;
    }
}

extern "C" void kernel_launch(void* const* d_in, const int* in_sizes, int n_in,
                              void* d_out, int out_size, void* d_ws, size_t ws_size,
                              hipStream_t stream)
{
    const float* start = (const float*)d_in[0];  // [8,256,256]
    const float* endl  = (const float*)d_in[1];  // [8,256,256]
    const float* cls   = (const float*)d_in[2];  // [8,16,256]
    const float* W     = (const float*)d_in[3];  // [256,256,256] (i,o,j)
    float* out = (float*)d_out;                  // [8,256,256,16]

    unsigned short* Wc  = (unsigned short*)d_ws;   // bf16 [128][256][256] = 16.7 MB
    unsigned short* T   = (unsigned short*)d_out;  // bf16 [128][256][256] in d_out scratch
    float*          tmp = (float*)d_ws;            // fp32 [128][256][256] over dead Wc

    // K1: Wc[bz,i,j] = sum_o cls[bz,o]*W[i,o,j].  batch=i(256). M=128(bz),N=256(j),K=256(o)
    hipLaunchKernelGGL((gemm_mfma<false, false, true, true>), dim3(2, 1, 256), dim3(512), 0, stream,
        (const void*)cls, (const void*)W, (void*)Wc,
        256, 256, 65536, 0L, 0, 65536L, 0, 256L);

    // K2: T[bz,x,j] = sum_i start[b,x,i]*Wc[bz,i,j].  batch=bz(128). M=N=K=256
    hipLaunchKernelGGL((gemm_mfma<false, true, true, true>), dim3(2, 2, 128), dim3(512), 0, stream,
        (const void*)start, (const void*)Wc, (void*)T,
        256, 256, 256, 65536L, 4, 65536L, 0, 65536L);

    // K3: tmp[bz,x,y] = sum_j T[bz,x,j]*end[b,y,j].  batch=bz(128). A@B^T
    hipLaunchKernelGGL((gemm_mfma<true, false, false, false>), dim3(2, 2, 128), dim3(512), 0, stream,
        (const void*)T, (const void*)endl, (void*)tmp,
        256, 256, 256, 65536L, 0, 65536L, 4, 65536L);

    // K4: z-transpose
    hipLaunchKernelGGL(ztranspose, dim3(2048), dim3(256), 0, stream, tmp, out);
}